// Round 3
// baseline (168.464 us; speedup 1.0000x reference)
//
#include <hip/hip_runtime.h>
#include <hip/hip_bf16.h>
#include <cstddef>
#include <cstdint>

#define D_MODEL   256
#define N_HEADS   8
#define N_LEVELS  4
#define N_POINTS  4
#define D_HEAD    32
#define HLP       128      // N_HEADS*N_LEVELS*N_POINTS
#define NBATCH    4
#define LQ        4096
#define S_LEN     7680     // 4096+2048+1024+512

typedef __attribute__((ext_vector_type(8))) short  short8;
typedef __attribute__((ext_vector_type(4))) float  f32x4;
typedef __attribute__((ext_vector_type(4))) int    i32x4;
typedef __attribute__((ext_vector_type(8))) unsigned short ushort8;

__device__ __forceinline__ unsigned short f2bf(float x) {
    __hip_bfloat16 h = __float2bfloat16(x);
    return *reinterpret_cast<unsigned short*>(&h);
}
__device__ __forceinline__ float bf2f(unsigned short u) {
    unsigned int v = ((unsigned int)u) << 16;
    return *reinterpret_cast<float*>(&v);
}

__device__ __forceinline__ void gload_lds16(const void* g, void* l) {
    __builtin_amdgcn_global_load_lds(
        (const __attribute__((address_space(1))) void*)g,
        (__attribute__((address_space(3))) void*)l,
        16, 0, 0);
}

// ---------------------------------------------------------------------------
// Fused weight prep: transpose [K=256][N] fp32 -> [N][K=256] bf16 for
// W_v (z=0), [W_off|W_aw] concat (z=1), W_out (z=2). Block (0,0,1) also
// writes bcat = [b_off|b_aw]. Grid (4,4,3), 256 threads.
// ---------------------------------------------------------------------------
__global__ __launch_bounds__(256) void prep_kernel(
    const float* __restrict__ W_v,  const float* __restrict__ W_off,
    const float* __restrict__ W_aw, const float* __restrict__ W_out,
    const float* __restrict__ b_off, const float* __restrict__ b_aw,
    unsigned short* __restrict__ Wv_t, unsigned short* __restrict__ Wcat_t,
    unsigned short* __restrict__ Wout_t, float* __restrict__ bcat)
{
    __shared__ float t[64][65];
    const int z   = blockIdx.z;
    const int k0  = blockIdx.y * 64;
    const int n0  = blockIdx.x * 64;
    const int tid = threadIdx.x;

    const float* src; int srcN; int cs; unsigned short* dst;
    if (z == 0)      { src = W_v;   srcN = 256; cs = n0;       dst = Wv_t;  }
    else if (z == 2) { src = W_out; srcN = 256; cs = n0;       dst = Wout_t;}
    else if (n0 < 128){ src = W_off; srcN = 128; cs = n0;      dst = Wcat_t;}
    else             { src = W_aw;  srcN = 128; cs = n0 - 128; dst = Wcat_t;}

    #pragma unroll
    for (int i = 0; i < 16; ++i) {
        int idx = tid + i * 256;
        int kk = idx >> 6, nn = idx & 63;
        t[kk][nn] = src[(size_t)(k0 + kk) * srcN + cs + nn];
    }
    __syncthreads();
    #pragma unroll
    for (int i = 0; i < 16; ++i) {
        int idx = tid + i * 256;
        int nn = idx >> 6, kk = idx & 63;
        dst[(size_t)(n0 + nn) * 256 + k0 + kk] = f2bf(t[kk][nn]);
    }
    if (z == 1 && blockIdx.x == 0 && blockIdx.y == 0) {
        bcat[tid] = (tid < 128) ? b_off[tid] : b_aw[tid - 128];
    }
}

// ---------------------------------------------------------------------------
// Pipelined value-GEMM + P-GEMM. 64x128 tiles, grid 1472, 256 thr (4 waves).
// job < 960 : value tile -> value3 bf16 [n][m][s][32]
// job >= 960: P tile     -> P fp32 [nq][256]
// ---------------------------------------------------------------------------
__global__ __launch_bounds__(256) void gemm_vp_kernel(
    const float* __restrict__ inflat, const float* __restrict__ query,
    const unsigned short* __restrict__ Wv_t, const unsigned short* __restrict__ Wcat_t,
    const float* __restrict__ b_v, const float* __restrict__ bcat,
    unsigned short* __restrict__ value3, float* __restrict__ P)
{
    __shared__ alignas(16) unsigned short Abuf[2][4][64][8];   // 2 x 4 KiB
    __shared__ alignas(16) unsigned short Bbuf[2][8][64][8];   // 2 x 8 KiB

    const int job = blockIdx.x;
    const bool is_val = (job < 960);
    const int jj   = is_val ? job : (job - 960);
    const int row0 = (jj >> 1) * 64;
    const int col0 = (jj & 1) * 128;
    const float* A = is_val ? inflat : query;
    const unsigned short* Bt = is_val ? Wv_t : Wcat_t;
    const float* bias = is_val ? b_v : bcat;

    const int tid  = threadIdx.x;
    const int lane = tid & 63;
    const int w    = tid >> 6;
    const int lr   = lane & 15;
    const int lk   = (lane >> 4) * 8;

    // A staging map: thread -> (row ar, k-offset ak), packed to frag order
    const int ar = tid >> 2;            // 0..63
    const int ak = (tid & 3) * 8;       // 0,8,16,24
    const int afrag = ar >> 4;
    const int alane = ((ak >> 3) << 4) | (ar & 15);
    const float* Arow = A + (size_t)(row0 + ar) * 256 + ak;
    const unsigned short* Bcol = Bt + (size_t)(col0 + lr) * 256 + lk;

    f32x4 acc[8] = {};

    // prologue: k-step 0
    float4 pa0 = *(const float4*)(Arow);
    float4 pa1 = *(const float4*)(Arow + 4);
    #pragma unroll
    for (int c = 0; c < 2; ++c) {
        const int in = w * 2 + c;
        gload_lds16(Bcol + (size_t)in * 16 * 256, &Bbuf[0][in][0][0]);
    }

    for (int kt = 0; kt < 8; ++kt) {
        const int cur = kt & 1;
        // pack A(kt) into frag-order LDS
        short8 pk;
        pk[0] = (short)f2bf(pa0.x); pk[1] = (short)f2bf(pa0.y);
        pk[2] = (short)f2bf(pa0.z); pk[3] = (short)f2bf(pa0.w);
        pk[4] = (short)f2bf(pa1.x); pk[5] = (short)f2bf(pa1.y);
        pk[6] = (short)f2bf(pa1.z); pk[7] = (short)f2bf(pa1.w);
        *(short8*)&Abuf[cur][afrag][alane][0] = pk;
        __syncthreads();   // drains DMA(kt) + A writes; all bufs[cur] ready

        if (kt < 7) {      // issue next-step loads AFTER barrier -> overlap
            const int k1 = (kt + 1) * 32;
            pa0 = *(const float4*)(Arow + k1);
            pa1 = *(const float4*)(Arow + k1 + 4);
            #pragma unroll
            for (int c = 0; c < 2; ++c) {
                const int in = w * 2 + c;
                gload_lds16(Bcol + (size_t)in * 16 * 256 + k1, &Bbuf[1 - cur][in][0][0]);
            }
        }

        const short8 af = *(const short8*)&Abuf[cur][w][lane][0];
        #pragma unroll
        for (int j = 0; j < 8; ++j) {
            const short8 bf = *(const short8*)&Bbuf[cur][j][lane][0];
            acc[j] = __builtin_amdgcn_mfma_f32_16x16x32_bf16(af, bf, acc[j], 0, 0, 0);
        }
        // no second barrier: next step writes the other buffer
    }

    const int prow = (lane >> 4) * 4;
    const int pcol = lane & 15;
    const int rbase = row0 + w * 16 + prow;
    if (is_val) {
        const int n  = row0 / S_LEN;
        const int s0 = row0 - n * S_LEN + w * 16 + prow;
        #pragma unroll
        for (int j = 0; j < 8; ++j) {
            const int col = col0 + j * 16 + pcol;
            const float bs = bias[col];
            const int m = col >> 5, d = col & 31;
            unsigned short* dst = value3 + ((size_t)(n * 8 + m) * S_LEN + s0) * 32 + d;
            #pragma unroll
            for (int r = 0; r < 4; ++r)
                dst[(size_t)r * 32] = f2bf(acc[j][r] + bs);
        }
    } else {
        #pragma unroll
        for (int j = 0; j < 8; ++j) {
            const int col = col0 + j * 16 + pcol;
            const float bs = bias[col];
            #pragma unroll
            for (int r = 0; r < 4; ++r)
                P[(size_t)(rbase + r) * 256 + col] = acc[j][r] + bs;
        }
    }
}

// ---------------------------------------------------------------------------
// FUSED sampling + softmax + out-projection, v2: latency-hiding rebuild.
// 1024 blocks x 512 threads (8 waves). Each block: 16 queries x 8 heads.
// Phase 1+2 FUSED, register-resident: one (q, head, 8-dim-group) task per
// thread. Each thread reads its own offsets/logits directly from P (the x4
// same-address reads across the ql quad are wave-merged -> no extra L2
// traffic), computes g0/w/softmax in registers, gathers, interpolates,
// writes its 8 bf16 dims to t_lds. NO staging LDS (was 25 KB), ONE barrier
// (was 2). LDS = 8.5 KB -> occupancy cap rises 16 -> ~24-32 waves/CU; the
// scattered-gather latency (L2-hit ~200cy) now has 2-3x more TLP to hide it.
// Phase 3: out[16][256] = t @ Wout_t^T + b_out, 8 waves x 32 cols.
// ---------------------------------------------------------------------------
__global__ __launch_bounds__(512, 4) void sample_out_kernel(
    const float* __restrict__ P, const float* __restrict__ refp,
    const int* __restrict__ shapes, const int* __restrict__ lstart,
    const unsigned short* __restrict__ value3,
    const unsigned short* __restrict__ Wout_t,
    const float* __restrict__ b_out,
    float* __restrict__ Cout)
{
    __shared__ alignas(16) unsigned short t_lds[16][264]; // padded bf16 t

    const int b    = blockIdx.x;       // 0..1023
    const int xcd  = b & 7;
    const int n    = xcd >> 1;         // batch
    const int half = xcd & 1;
    const int slot = b >> 3;           // 0..127
    const int q0   = (slot * 2 + half) * 16;
    const int nq0  = n * LQ + q0;
    const int tid  = threadIdx.x;

    // ---- phase 1+2 fused: one (q, m, ql) per thread, all in registers ----
    {
        const int q   = tid >> 5;         // 0..15
        const int sub = tid & 31;
        const int m   = sub >> 2;         // head
        const int ql  = sub & 3;          // 8-dim group
        const int nq  = nq0 + q;

        const i32x4 sh4 = *(const i32x4*)shapes;
        const i32x4 ls4 = *(const i32x4*)lstart;
        const f32x4 rf4 = *(const f32x4*)(refp + (size_t)nq * N_LEVELS);

        float e[16], wgt[16];
        int   g0a[16], glim[4];
        #pragma unroll
        for (int l = 0; l < 4; ++l) {
            const f32x4 off = __builtin_nontemporal_load(
                (const f32x4*)(P + (size_t)nq * 256 + m * 16 + l * 4));
            const f32x4 lg  = __builtin_nontemporal_load(
                (const f32x4*)(P + (size_t)nq * 256 + 128 + m * 16 + l * 4));
            const float Tf = (float)sh4[l];
            glim[l] = ls4[l] + sh4[l] - 1;
            #pragma unroll
            for (int k = 0; k < 4; ++k) {
                float x = rf4[l] * Tf + off[k] - 0.5f;
                x = fminf(fmaxf(x, 0.0f), Tf - 1.0f);
                const float x0 = floorf(x);
                g0a[l * 4 + k] = (int)x0 + ls4[l];
                wgt[l * 4 + k] = x - x0;
                e  [l * 4 + k] = lg[k];
            }
        }

        float mx = -1e30f;
        #pragma unroll
        for (int i = 0; i < 16; ++i) mx = fmaxf(mx, e[i]);
        float s = 0.f;
        #pragma unroll
        for (int i = 0; i < 16; ++i) { e[i] = __expf(e[i] - mx); s += e[i]; }
        const float rs = 1.0f / s;

        const unsigned short* vb =
            value3 + (size_t)(n * 8 + m) * S_LEN * 32 + ql * 8;

        float acc[8] = {};
        #pragma unroll
        for (int i = 0; i < 16; ++i) {
            const float a  = e[i] * rs;
            const float ww = wgt[i];
            const int g0 = g0a[i];
            const int g1 = min(g0 + 1, glim[i >> 2]);
            const ushort8 u0 = *(const ushort8*)(vb + (size_t)g0 * 32);
            const ushort8 u1 = *(const ushort8*)(vb + (size_t)g1 * 32);
            #pragma unroll
            for (int d = 0; d < 8; ++d) {
                const float v0 = bf2f(u0[d]);
                const float v1 = bf2f(u1[d]);
                acc[d] += a * (v0 + ww * (v1 - v0));
            }
        }
        ushort8 o;
        #pragma unroll
        for (int d = 0; d < 8; ++d) o[d] = f2bf(acc[d]);
        *(ushort8*)&t_lds[q][m * 32 + ql * 8] = o;
    }
    __syncthreads();

    // ---- phase 3: out[16][256] = t @ Wout_t^T + b_out, 8 waves x 32 cols --
    const int lane = tid & 63;
    const int wv   = tid >> 6;          // wave 0..7 -> 32-col slice
    const int arow = lane & 15;         // A row (query)
    const int kgrp = (lane >> 4) * 8;   // A/B k sub-offset
    const int n0   = wv * 32;

    // hoist A fragments: af[kt] = t row 'arow', k = kt*32 + kgrp
    short8 af[8];
    #pragma unroll
    for (int kt = 0; kt < 8; ++kt)
        af[kt] = *(const short8*)&t_lds[arow][kt * 32 + kgrp];

    f32x4 oacc[2] = {};
    #pragma unroll
    for (int j = 0; j < 2; ++j) {
        const unsigned short* bp =
            Wout_t + (size_t)(n0 + j * 16 + arow) * 256 + kgrp;
        #pragma unroll
        for (int kt = 0; kt < 8; ++kt) {
            const short8 bf = *(const short8*)(bp + kt * 32);
            oacc[j] = __builtin_amdgcn_mfma_f32_16x16x32_bf16(af[kt], bf, oacc[j], 0, 0, 0);
        }
    }

    const int prow = (lane >> 4) * 4;   // acc row base (query)
    const int pcol = lane & 15;
    #pragma unroll
    for (int j = 0; j < 2; ++j) {
        const int col = n0 + j * 16 + pcol;
        const float bs = b_out[col];
        #pragma unroll
        for (int r = 0; r < 4; ++r)
            __builtin_nontemporal_store(oacc[j][r] + bs,
                Cout + (size_t)(nq0 + prow + r) * 256 + col);
    }
}

// ---------------------------------------------------------------------------
extern "C" void kernel_launch(void* const* d_in, const int* in_sizes, int n_in,
                              void* d_out, int out_size, void* d_ws, size_t ws_size,
                              hipStream_t stream)
{
    const float* query  = (const float*)d_in[0];
    const float* refp   = (const float*)d_in[1];
    const float* inflat = (const float*)d_in[2];
    const int*   shapes = (const int*)d_in[3];
    const int*   lstart = (const int*)d_in[4];
    const float* W_off  = (const float*)d_in[5];
    const float* b_off  = (const float*)d_in[6];
    const float* W_aw   = (const float*)d_in[7];
    const float* b_aw   = (const float*)d_in[8];
    const float* W_v    = (const float*)d_in[9];
    const float* b_v    = (const float*)d_in[10];
    const float* W_out  = (const float*)d_in[11];
    const float* b_out  = (const float*)d_in[12];

    const int M_val = NBATCH * S_LEN;    // 30720
    const int M_q   = NBATCH * LQ;       // 16384

    // ---- workspace layout ----
    char* p = (char*)d_ws;
    unsigned short* value3 = (unsigned short*)p; p += (size_t)M_val * D_MODEL * 2; // 15.7 MB
    float*          P      = (float*)p;          p += (size_t)M_q * 256 * 4;       // 16.8 MB
    unsigned short* Wv_t   = (unsigned short*)p; p += 256 * 256 * 2;
    unsigned short* Wcat_t = (unsigned short*)p; p += 256 * 256 * 2;
    unsigned short* Wout_t = (unsigned short*)p; p += 256 * 256 * 2;
    float*          bcat   = (float*)p;          p += 256 * 4;

    // 1. weight prep
    prep_kernel<<<dim3(4, 4, 3), 256, 0, stream>>>(
        W_v, W_off, W_aw, W_out, b_off, b_aw, Wv_t, Wcat_t, Wout_t, bcat);
    // 2. value-GEMM (960 jobs) + P-GEMM (512 jobs), one pipelined dispatch
    gemm_vp_kernel<<<1472, 256, 0, stream>>>(
        inflat, query, Wv_t, Wcat_t, b_v, bcat, value3, P);
    // 3. fused sampling + softmax + out-projection -> d_out
    sample_out_kernel<<<1024, 512, 0, stream>>>(
        P, refp, shapes, lstart, value3, Wout_t, b_out, (float*)d_out);
}